// Round 1
// baseline (135.097 us; speedup 1.0000x reference)
//
#include <hip/hip_runtime.h>
#include <math.h>

// FastFeedForward (FFF) fused forward, MI355X.
// B=4,S=4096,D=768, depth=11, n_nodes=21.
// Key exact simplification: with n=21 and clip(·,0,20), the traversal node
// saturates at 20 from level 5 onward, so steps t=4..9 collapse into
// (gelu(lam4) + 5*gelu(lam20)) * w_out[20]. Only <=6 dots + 5 row-accs/token.

#define D 768
#define NF4 (D / 4)      // 192 float4 per row
#define NN 21
#define TPB 1024         // 16 waves/block
#define NBLK 256         // 1 block per CU (126 KB LDS)
#define WAVES_TOTAL (NBLK * (TPB / 64))  // 4096

__device__ __forceinline__ float gelu_exact(float v) {
  return 0.5f * v * (1.0f + erff(v * 0.70710678118654752440f));
}

__device__ __forceinline__ double wave_sum(double v) {
#pragma unroll
  for (int off = 32; off > 0; off >>= 1) v += __shfl_xor(v, off, 64);
  return v;
}

// Per-lane 12-elem partial dot (f64 accum; f32*f32 is exact in f64), then
// full-wave reduction. Result is wave-uniform.
__device__ __forceinline__ double dot_row(float4 x0, float4 x1, float4 x2,
                                          const float* __restrict__ row,
                                          int lane) {
  const float4* r = (const float4*)row;
  float4 w0 = r[lane];
  float4 w1 = r[lane + 64];
  float4 w2 = r[lane + 128];
  double s = (double)x0.x * (double)w0.x;
  s = fma((double)x0.y, (double)w0.y, s);
  s = fma((double)x0.z, (double)w0.z, s);
  s = fma((double)x0.w, (double)w0.w, s);
  s = fma((double)x1.x, (double)w1.x, s);
  s = fma((double)x1.y, (double)w1.y, s);
  s = fma((double)x1.z, (double)w1.z, s);
  s = fma((double)x1.w, (double)w1.w, s);
  s = fma((double)x2.x, (double)w2.x, s);
  s = fma((double)x2.y, (double)w2.y, s);
  s = fma((double)x2.z, (double)w2.z, s);
  s = fma((double)x2.w, (double)w2.w, s);
  return wave_sum(s);
}

#define ACC4(av, wv)                 \
  av.x = fmaf(g, wv.x, av.x);        \
  av.y = fmaf(g, wv.y, av.y);        \
  av.z = fmaf(g, wv.z, av.z);        \
  av.w = fmaf(g, wv.w, av.w)

__global__ __launch_bounds__(TPB, 4) void fff_kernel(
    const float* __restrict__ x, const float* __restrict__ wi,
    const float* __restrict__ wo, float* __restrict__ out, int ntok) {
  __shared__ float s_wi[NN * D];  // 63 KB
  __shared__ float s_wo[NN * D];  // 63 KB

  const int tid = threadIdx.x;
  // Cooperative stage of both weight matrices (float4, coalesced).
  {
    const float4* a = (const float4*)wi;
    const float4* b = (const float4*)wo;
    float4* sa = (float4*)s_wi;
    float4* sb = (float4*)s_wo;
    for (int i = tid; i < NN * NF4; i += TPB) {
      sa[i] = a[i];
      sb[i] = b[i];
    }
  }
  __syncthreads();

  const int lane = tid & 63;
  const int wid = (blockIdx.x << 4) | (tid >> 6);  // global wave id, 0..4095

  for (int tok = wid; tok < ntok; tok += WAVES_TOTAL) {
    const float4* xp = (const float4*)(x + (size_t)tok * D);
    float4 x0 = xp[lane];
    float4 x1 = xp[lane + 64];
    float4 x2 = xp[lane + 128];

    float4 a0 = {0.f, 0.f, 0.f, 0.f};
    float4 a1 = {0.f, 0.f, 0.f, 0.f};
    float4 a2 = {0.f, 0.f, 0.f, 0.f};

    int u = 0;
    // Steps t=0..3: distinct nodes, each contributes gelu(lam_t)*w_out[u_{t+1}].
#pragma unroll
    for (int t = 0; t < 4; ++t) {
      double lam = dot_row(x0, x1, x2, s_wi + u * D, lane);
      float lf = (float)lam;
      float g = gelu_exact(lf);
      u = 2 * u + 1 + (lf > 0.0f);
      u = min(u, NN - 1);  // only active at t==3
      const float4* r = (const float4*)(s_wo + u * D);
      float4 w0 = r[lane];
      float4 w1 = r[lane + 64];
      float4 w2 = r[lane + 128];
      ACC4(a0, w0);
      ACC4(a1, w1);
      ACC4(a2, w2);
    }
    // Step t=4 at u in {15..20}; u5..u10 == 20. Steps 4..9 all hit w_out[20].
    double lam4 = dot_row(x0, x1, x2, s_wi + u * D, lane);
    float g4 = gelu_exact((float)lam4);
    double lam20 =
        (u == NN - 1) ? lam4 : dot_row(x0, x1, x2, s_wi + (NN - 1) * D, lane);
    float g20 = gelu_exact((float)lam20);
    float g = g4 + 5.0f * g20;  // coefficient of w_out[20]
    {
      const float4* r = (const float4*)(s_wo + (NN - 1) * D);
      float4 w0 = r[lane];
      float4 w1 = r[lane + 64];
      float4 w2 = r[lane + 128];
      ACC4(a0, w0);
      ACC4(a1, w1);
      ACC4(a2, w2);
    }

    float4* op = (float4*)(out + (size_t)tok * D);
    op[lane] = a0;
    op[lane + 64] = a1;
    op[lane + 128] = a2;
  }
}

extern "C" void kernel_launch(void* const* d_in, const int* in_sizes, int n_in,
                              void* d_out, int out_size, void* d_ws,
                              size_t ws_size, hipStream_t stream) {
  const float* x = (const float*)d_in[0];
  const float* wi = (const float*)d_in[1];
  const float* wo = (const float*)d_in[2];
  float* out = (float*)d_out;
  const int ntok = in_sizes[0] / D;  // 16384
  fff_kernel<<<NBLK, TPB, 0, stream>>>(x, wi, wo, out, ntok);
}